// Round 6
// baseline (413.432 us; speedup 1.0000x reference)
//
#include <hip/hip_runtime.h>
#include <cstdint>
#include <cstddef>

// MultiHeadSelfAttention forward, MI355X/gfx950.  Round 6.
//  - attn: 256 q-rows per block (512 thr, 8 waves x 2 groups of 16 rows) ->
//    4x less K/V HBM traffic; chunked XCD mapping keeps each (b,h)'s KV in one
//    XCD's L2; fully-masked group-tiles skipped; swapped-QK^T softmax (R5).
//  - gemm_out: Wo pre-converted to bf16 (into Qb, dead after attn) so both
//    operands stage via global_load_lds width-16.
//
// Frag layouts (verified, mfma_f32_16x16x32_bf16):
//   C/D: row = (lane>>4)*4 + j, col = lane&15
//   A:   row = lane&15,        k = (lane>>4)*8 + j
//   B:   col = lane&15,        k = (lane>>4)*8 + j

typedef __attribute__((ext_vector_type(8))) short bf16x8;
typedef __attribute__((ext_vector_type(4))) float f32x4;

#define LOG2E 1.4426950408889634f

__device__ __forceinline__ unsigned short f2bf(float f) {
  unsigned int u = __builtin_bit_cast(unsigned int, f);
  unsigned int r = (u + 0x7FFFu + ((u >> 16) & 1u)) >> 16;  // RNE
  return (unsigned short)r;
}
__device__ __forceinline__ float bf2f(unsigned short h) {
  return __builtin_bit_cast(float, (unsigned int)h << 16);
}
__device__ __forceinline__ unsigned int packbf2(float a, float b) {
  return (unsigned int)f2bf(a) | ((unsigned int)f2bf(b) << 16);
}
// XOR swizzle for [R][64]-ushort row-major LDS tiles: byte ^= ((row&7)<<4).
__device__ __forceinline__ int swz(int idx) {
  return idx ^ (((idx >> 6) & 7) << 3);
}

// ---------------- fp32 -> bf16 bulk converts ----------------
__global__ __launch_bounds__(256) void cvt_kernel(const float* __restrict__ in,
                                                  unsigned short* __restrict__ out,
                                                  int n8) {
  int i = blockIdx.x * 256 + threadIdx.x;
  if (i < n8) {
    float4 u0 = ((const float4*)in)[i * 2];
    float4 u1 = ((const float4*)in)[i * 2 + 1];
    uint4 v = {packbf2(u0.x, u0.y), packbf2(u0.z, u0.w),
               packbf2(u1.x, u1.y), packbf2(u1.z, u1.w)};
    ((uint4*)out)[i] = v;
  }
}
// Convert Wq/Wk/Wv (1M fp32 each) -> bf16, dst selected by blockIdx.y.
__global__ __launch_bounds__(256) void cvt_w3(const float* __restrict__ w0,
                                              const float* __restrict__ w1,
                                              const float* __restrict__ w2,
                                              unsigned short* __restrict__ dst) {
  const float* src = blockIdx.y == 0 ? w0 : (blockIdx.y == 1 ? w1 : w2);
  unsigned short* d = dst + (size_t)blockIdx.y * 1024 * 1024;
  int i = blockIdx.x * 256 + threadIdx.x;
  float4 u0 = ((const float4*)src)[i * 2];
  float4 u1 = ((const float4*)src)[i * 2 + 1];
  uint4 v = {packbf2(u0.x, u0.y), packbf2(u0.z, u0.w),
             packbf2(u1.x, u1.y), packbf2(u1.z, u1.w)};
  ((uint4*)d)[i] = v;
}

// ---------------- fused QKV GEMM ----------------
// C = Xb[8192,1024](bf16) * W[3072,1024]^T(bf16). 128x128 tile, BK=64, 4 waves.
__global__ __launch_bounds__(256) void gemm_qkv(const unsigned short* __restrict__ Xb,
                                                const unsigned short* __restrict__ Wb3,
                                                unsigned short* __restrict__ Qb,
                                                unsigned short* __restrict__ Kb,
                                                unsigned short* __restrict__ Vtb) {
  __shared__ alignas(16) unsigned short As[128 * 64];
  __shared__ alignas(16) unsigned short Bs[128 * 64];
  const int t = threadIdx.x;
  const int lane = t & 63;
  const int w = t >> 6;
  const int wr = w >> 1, wc = w & 1;
  const int fr = lane & 15, fq = lane >> 4;
  const int m0 = blockIdx.x * 128;
  const int sel = blockIdx.y >> 3;
  const int n0 = (blockIdx.y & 7) * 128;
  const unsigned short* Wp = Wb3 + (size_t)sel * 1024 * 1024;
  const int K = 1024;

  const f32x4 zero = {0.f, 0.f, 0.f, 0.f};
  f32x4 acc[4][4];
#pragma unroll
  for (int m = 0; m < 4; ++m)
#pragma unroll
    for (int n = 0; n < 4; ++n) acc[m][n] = zero;

  for (int k0 = 0; k0 < K; k0 += 64) {
#pragma unroll
    for (int cc = 0; cc < 4; ++cc) {
      int c = w * 4 + cc;
      int flat = c * 512 + lane * 8;
      int row = flat >> 6, col = flat & 63;
      __builtin_amdgcn_global_load_lds(
          (const __attribute__((address_space(1))) void*)(Xb + (size_t)(m0 + row) * K + (k0 + col)),
          (__attribute__((address_space(3))) void*)&As[c * 512], 16, 0, 0);
      __builtin_amdgcn_global_load_lds(
          (const __attribute__((address_space(1))) void*)(Wp + (size_t)(n0 + row) * K + (k0 + col)),
          (__attribute__((address_space(3))) void*)&Bs[c * 512], 16, 0, 0);
    }
    __syncthreads();
#pragma unroll
    for (int kk = 0; kk < 2; ++kk) {
      bf16x8 a[4], b[4];
#pragma unroll
      for (int m = 0; m < 4; ++m)
        a[m] = *(const bf16x8*)&As[(wr * 64 + m * 16 + fr) * 64 + kk * 32 + fq * 8];
#pragma unroll
      for (int n = 0; n < 4; ++n)
        b[n] = *(const bf16x8*)&Bs[(wc * 64 + n * 16 + fr) * 64 + kk * 32 + fq * 8];
#pragma unroll
      for (int m = 0; m < 4; ++m)
#pragma unroll
        for (int n = 0; n < 4; ++n)
          acc[m][n] = __builtin_amdgcn_mfma_f32_16x16x32_bf16(a[m], b[n], acc[m][n], 0, 0, 0);
    }
    __syncthreads();
  }

#pragma unroll
  for (int m = 0; m < 4; ++m)
#pragma unroll
    for (int n = 0; n < 4; ++n) {
      int row = m0 + wr * 64 + m * 16 + fq * 4;
      int col = n0 + wc * 64 + n * 16 + fr;
      if (sel < 2) {
        unsigned short* Cp = sel ? Kb : Qb;
#pragma unroll
        for (int j = 0; j < 4; ++j)
          Cp[(size_t)(row + j) * 1024 + col] = f2bf(acc[m][n][j]);
      } else {
        int b = row >> 11, s = row & 2047;
        int h = col >> 6, d = col & 63;
        ushort4 v4 = {f2bf(acc[m][n][0]), f2bf(acc[m][n][1]),
                      f2bf(acc[m][n][2]), f2bf(acc[m][n][3])};
        *(ushort4*)&Vtb[(((size_t)b * 16 + h) * 64 + d) * 2048 + s] = v4;
      }
    }
}

// ---------------- RoPE (in-place, 4 pairs/thread) ----------------
// Q additionally scaled by (1/sqrt(d_k))*log2(e) so attn can use exp2 directly.
__global__ __launch_bounds__(256) void rope_kernel(unsigned short* __restrict__ Q,
                                                   unsigned short* __restrict__ Kb,
                                                   const int* __restrict__ tp) {
  int idx = blockIdx.x * 256 + threadIdx.x;
  unsigned short* ptr = blockIdx.y ? Kb : Q;
  const float scale = blockIdx.y ? 1.0f : 0.125f * LOG2E;
  int flat8 = idx * 8;
  int r = flat8 >> 10;
  int colbase = flat8 & 1023;
  int ibase = (colbase & 63) >> 1;
  int s = r & 2047;
  float pos = (float)tp[s];
  const float cexp = -13.287712379549449f / 32.0f;  // -log2(theta)/32

  uint4 v = *(const uint4*)&ptr[flat8];
  unsigned int* vp = (unsigned int*)&v;
  uint4 o;
  unsigned int* op = (unsigned int*)&o;
#pragma unroll
  for (int p = 0; p < 4; ++p) {
    float inv = exp2f((float)(ibase + p) * cexp);
    float ang = pos * inv;
    float sn, cs;
    sincosf(ang, &sn, &cs);
    float x1 = bf2f((unsigned short)(vp[p] & 0xFFFFu));
    float x2 = bf2f((unsigned short)(vp[p] >> 16));
    op[p] = packbf2((x1 * cs - x2 * sn) * scale, (x1 * sn + x2 * cs) * scale);
  }
  *(uint4*)&ptr[flat8] = o;
}

// ---------------- Flash attention, causal, 256 q-rows/block ----------------
// 512 threads = 8 waves; wave w owns q-rows q0+w*32 .. +31 (2 groups of 16).
// Swapped QK^T: lane's q = fr; kv = n*16+fq*4+j. Chunked XCD block mapping.
__global__ __launch_bounds__(512, 2) void attn_kernel(const unsigned short* __restrict__ Q,
                                                      const unsigned short* __restrict__ K,
                                                      const unsigned short* __restrict__ Vt_g,
                                                      unsigned short* __restrict__ O) {
  __shared__ alignas(16) unsigned short Ks[64 * 64];
  __shared__ alignas(16) unsigned short Vt[64 * 64];   // [d][kv]
  const int t = threadIdx.x;
  const int lane = t & 63, w = t >> 6;
  const int fr = lane & 15, fq = lane >> 4;
  // chunked XCD mapping: 512 blocks, XCD k gets gblk in [64k, 64k+64)
  // = 8 whole (b,h) groups (8 q-tiles each) -> KV L2-resident per XCD.
  const int gblk = (blockIdx.x & 7) * 64 + (blockIdx.x >> 3);
  const int qt = gblk & 7;
  const int hb = gblk >> 3;
  const int h = hb & 15, b = hb >> 4;
  const int q0 = qt * 256;
  const size_t base = ((size_t)b * 2048) * 1024 + (size_t)h * 64;
  const size_t vbase = ((size_t)b * 16 + h) * 64 * 2048;
  const f32x4 zero = {0.f, 0.f, 0.f, 0.f};

  // Q frags straight from global (16B contiguous per lane).
  bf16x8 qf[2][2];
#pragma unroll
  for (int g = 0; g < 2; ++g)
#pragma unroll
    for (int kk = 0; kk < 2; ++kk)
      qf[g][kk] = *(const bf16x8*)&Q[base + (size_t)(q0 + w * 32 + g * 16 + fr) * 1024 + kk * 32 + fq * 8];

  float m_[2] = {-INFINITY, -INFINITY};
  float l_[2] = {0.f, 0.f};
  f32x4 oaccT[2][4];
#pragma unroll
  for (int g = 0; g < 2; ++g)
#pragma unroll
    for (int n = 0; n < 4; ++n) oaccT[g][n] = zero;

  const int sflat = t * 8;               // 512 thr x 8 elems = 64x64 tile
  const int srow = sflat >> 6, scol = sflat & 63;
  const int sdst = swz(sflat);
  uint4 kr = *(const uint4*)&K[base + (size_t)srow * 1024 + scol];
  uint4 vr = *(const uint4*)&Vt_g[vbase + (size_t)srow * 2048 + scol];
  const int kvend = q0 + 256;
  const int wq = q0 + w * 32;

  for (int kv0 = 0; kv0 < kvend; kv0 += 64) {
    __syncthreads();
    *(uint4*)&Ks[sdst] = kr;
    *(uint4*)&Vt[sdst] = vr;
    __syncthreads();
    if (kv0 + 64 < kvend) {
      kr = *(const uint4*)&K[base + (size_t)(kv0 + 64 + srow) * 1024 + scol];
      vr = *(const uint4*)&Vt_g[vbase + (size_t)srow * 2048 + kv0 + 64 + scol];
    }

    if (kv0 <= wq + 31) {  // some group in this wave still has unmasked kv
      // shared K frags for both groups
      bf16x8 kf[2][4];
#pragma unroll
      for (int kk = 0; kk < 2; ++kk)
#pragma unroll
        for (int n = 0; n < 4; ++n)
          kf[kk][n] = *(const bf16x8*)&Ks[swz((n * 16 + fr) * 64 + kk * 32 + fq * 8)];

#pragma unroll
      for (int g = 0; g < 2; ++g) {
        if (kv0 > wq + g * 16 + 15) continue;  // fully masked for this group
        // ---- S^T = K Q^T ----
        f32x4 sa[4];
#pragma unroll
        for (int n = 0; n < 4; ++n) sa[n] = zero;
#pragma unroll
        for (int kk = 0; kk < 2; ++kk)
#pragma unroll
          for (int n = 0; n < 4; ++n)
            sa[n] = __builtin_amdgcn_mfma_f32_16x16x32_bf16(kf[kk][n], qf[g][kk], sa[n], 0, 0, 0);

        // ---- causal mask + online softmax (exp2 domain; row local to lane) ----
        const int dd = kv0 - wq - g * 16;    // kv_global - q_base of group
        const bool diag = (dd > -63);
        float pmax = -3.0e38f;
#pragma unroll
        for (int n = 0; n < 4; ++n)
#pragma unroll
          for (int j = 0; j < 4; ++j) {
            float s = sa[n][j];
            if (diag && (n * 16 + fq * 4 + j + dd > fr)) s = -3.0e38f;
            sa[n][j] = s;
            pmax = fmaxf(pmax, s);
          }
        pmax = fmaxf(pmax, __shfl_xor(pmax, 16));
        pmax = fmaxf(pmax, __shfl_xor(pmax, 32));
        float mn = fmaxf(m_[g], pmax);
        float alpha = exp2f(m_[g] - mn);
        m_[g] = mn;
        float ps = 0.f;
#pragma unroll
        for (int n = 0; n < 4; ++n)
#pragma unroll
          for (int j = 0; j < 4; ++j) {
            float e = exp2f(sa[n][j] - mn);
            sa[n][j] = e;
            ps += e;
          }
        ps += __shfl_xor(ps, 16);
        ps += __shfl_xor(ps, 32);
        l_[g] = l_[g] * alpha + ps;
#pragma unroll
        for (int n = 0; n < 4; ++n)
#pragma unroll
          for (int j = 0; j < 4; ++j) oaccT[g][n][j] *= alpha;

        // ---- P^T -> PV B-frag: in-register butterfly (verified R4/R5) ----
        unsigned R[4][2], F[4][2];
#pragma unroll
        for (int n = 0; n < 4; ++n)
#pragma unroll
          for (int pp = 0; pp < 2; ++pp)
            R[n][pp] = packbf2(sa[n][2 * pp], sa[n][2 * pp + 1]);
#pragma unroll
        for (int pp = 0; pp < 2; ++pp) {
          unsigned t0 = (fq < 2) ? R[1][pp] : R[0][pp];
          unsigned t1 = (fq < 2) ? R[3][pp] : R[2][pp];
          t0 = (unsigned)__shfl_xor((int)t0, 32);
          t1 = (unsigned)__shfl_xor((int)t1, 32);
          unsigned G0 = (fq < 2) ? R[0][pp] : t0;
          unsigned G1 = (fq < 2) ? t0 : R[1][pp];
          unsigned G2 = (fq < 2) ? R[2][pp] : t1;
          unsigned G3 = (fq < 2) ? t1 : R[3][pp];
          unsigned u0 = ((fq & 1) == 0) ? G1 : G0;
          unsigned u1 = ((fq & 1) == 0) ? G3 : G2;
          u0 = (unsigned)__shfl_xor((int)u0, 16);
          u1 = (unsigned)__shfl_xor((int)u1, 16);
          F[0][pp] = ((fq & 1) == 0) ? G0 : u0;
          F[1][pp] = ((fq & 1) == 0) ? u0 : G1;
          F[2][pp] = ((fq & 1) == 0) ? G2 : u1;
          F[3][pp] = ((fq & 1) == 0) ? u1 : G3;
        }
        union U8 { unsigned u[4]; bf16x8 v; };
        U8 pb0, pb1;
        pb0.u[0] = F[0][0]; pb0.u[1] = F[0][1]; pb0.u[2] = F[1][0]; pb0.u[3] = F[1][1];
        pb1.u[0] = F[2][0]; pb1.u[1] = F[2][1]; pb1.u[2] = F[3][0]; pb1.u[3] = F[3][1];

        // ---- O^T += V^T P^T ----
#pragma unroll
        for (int n = 0; n < 4; ++n) {
          bf16x8 vf0 = *(const bf16x8*)&Vt[swz((n * 16 + fr) * 64 + 0 * 32 + fq * 8)];
          oaccT[g][n] = __builtin_amdgcn_mfma_f32_16x16x32_bf16(vf0, pb0.v, oaccT[g][n], 0, 0, 0);
          bf16x8 vf1 = *(const bf16x8*)&Vt[swz((n * 16 + fr) * 64 + 1 * 32 + fq * 8)];
          oaccT[g][n] = __builtin_amdgcn_mfma_f32_16x16x32_bf16(vf1, pb1.v, oaccT[g][n], 0, 0, 0);
        }
      }
    }
  }

  // ---- epilogue ----
#pragma unroll
  for (int g = 0; g < 2; ++g) {
    float rl = 1.0f / l_[g];
#pragma unroll
    for (int n = 0; n < 4; ++n) {
      ushort4 v4 = {f2bf(oaccT[g][n][0] * rl), f2bf(oaccT[g][n][1] * rl),
                    f2bf(oaccT[g][n][2] * rl), f2bf(oaccT[g][n][3] * rl)};
      *(ushort4*)&O[base + (size_t)(q0 + w * 32 + g * 16 + fr) * 1024 + n * 16 + fq * 4] = v4;
    }
  }
}

// ---------------- out GEMM: C fp32 = A(bf16) * W(bf16)^T ----------------
__global__ __launch_bounds__(256) void gemm_out_bf(const unsigned short* __restrict__ Ap,
                                                   const unsigned short* __restrict__ Wp,
                                                   float* __restrict__ Cp) {
  __shared__ alignas(16) unsigned short As[128 * 64];
  __shared__ alignas(16) unsigned short Bs[128 * 64];
  const int t = threadIdx.x;
  const int lane = t & 63;
  const int w = t >> 6;
  const int wr = w >> 1, wc = w & 1;
  const int fr = lane & 15, fq = lane >> 4;
  const int m0 = blockIdx.x * 128, n0 = blockIdx.y * 128;
  const int K = 1024, N = 1024;

  const f32x4 zero = {0.f, 0.f, 0.f, 0.f};
  f32x4 acc[4][4];
#pragma unroll
  for (int m = 0; m < 4; ++m)
#pragma unroll
    for (int n = 0; n < 4; ++n) acc[m][n] = zero;

  for (int k0 = 0; k0 < K; k0 += 64) {
#pragma unroll
    for (int cc = 0; cc < 4; ++cc) {
      int c = w * 4 + cc;
      int flat = c * 512 + lane * 8;
      int row = flat >> 6, col = flat & 63;
      __builtin_amdgcn_global_load_lds(
          (const __attribute__((address_space(1))) void*)(Ap + (size_t)(m0 + row) * K + (k0 + col)),
          (__attribute__((address_space(3))) void*)&As[c * 512], 16, 0, 0);
      __builtin_amdgcn_global_load_lds(
          (const __attribute__((address_space(1))) void*)(Wp + (size_t)(n0 + row) * K + (k0 + col)),
          (__attribute__((address_space(3))) void*)&Bs[c * 512], 16, 0, 0);
    }
    __syncthreads();
#pragma unroll
    for (int kk = 0; kk < 2; ++kk) {
      bf16x8 a[4], b[4];
#pragma unroll
      for (int m = 0; m < 4; ++m)
        a[m] = *(const bf16x8*)&As[(wr * 64 + m * 16 + fr) * 64 + kk * 32 + fq * 8];
#pragma unroll
      for (int n = 0; n < 4; ++n)
        b[n] = *(const bf16x8*)&Bs[(wc * 64 + n * 16 + fr) * 64 + kk * 32 + fq * 8];
#pragma unroll
      for (int m = 0; m < 4; ++m)
#pragma unroll
        for (int n = 0; n < 4; ++n)
          acc[m][n] = __builtin_amdgcn_mfma_f32_16x16x32_bf16(a[m], b[n], acc[m][n], 0, 0, 0);
    }
    __syncthreads();
  }

#pragma unroll
  for (int m = 0; m < 4; ++m)
#pragma unroll
    for (int n = 0; n < 4; ++n) {
      int row = m0 + wr * 64 + m * 16 + fq * 4;
      int col = n0 + wc * 64 + n * 16 + fr;
#pragma unroll
      for (int j = 0; j < 4; ++j)
        Cp[(size_t)(row + j) * N + col] = acc[m][n][j];
    }
}

extern "C" void kernel_launch(void* const* d_in, const int* in_sizes, int n_in,
                              void* d_out, int out_size, void* d_ws, size_t ws_size,
                              hipStream_t stream) {
  const float* x  = (const float*)d_in[0];
  const int* tp   = (const int*)d_in[1];
  const float* Wq = (const float*)d_in[2];
  const float* Wk = (const float*)d_in[3];
  const float* Wv = (const float*)d_in[4];
  const float* Wo = (const float*)d_in[5];
  float* out = (float*)d_out;

  const size_t MAT = (size_t)8192 * 1024;
  unsigned short* Qb  = (unsigned short*)d_ws;
  unsigned short* Kb  = Qb + MAT;
  unsigned short* Vtb = Kb + MAT;          // V^T (B,H,64,2048)
  unsigned short* Xb  = Vtb + MAT;         // x bf16; reused as Ob after gemm_qkv
  unsigned short* Ob  = Xb;
  unsigned short* Wb3 = (unsigned short*)d_out;  // Wq/Wk/Wv bf16 (6 MB of 32 MB, dead before gemm_out)
  unsigned short* WoB = Qb;                // Wo bf16 after attn (Qb dead)

  cvt_kernel<<<4096, 256, 0, stream>>>(x, Xb, 8192 * 1024 / 8);
  cvt_w3<<<dim3(512, 3), 256, 0, stream>>>(Wq, Wk, Wv, Wb3);
  gemm_qkv<<<dim3(64, 24), 256, 0, stream>>>(Xb, Wb3, Qb, Kb, Vtb);
  rope_kernel<<<dim3(4096, 2), 256, 0, stream>>>(Qb, Kb, tp);
  attn_kernel<<<512, 512, 0, stream>>>(Qb, Kb, Vtb, Ob);
  cvt_kernel<<<512, 256, 0, stream>>>(Wo, WoB, 1024 * 1024 / 8);
  gemm_out_bf<<<dim3(64, 8), 256, 0, stream>>>(Ob, WoB, out);
}

// Round 9
// 364.197 us; speedup vs baseline: 1.1352x; 1.1352x over previous
//
#include <hip/hip_runtime.h>
#include <cstdint>
#include <cstddef>

// MultiHeadSelfAttention forward, MI355X/gfx950.  Round 7 (3rd submit; infra timeouts).
//  - attn: 128 q-rows per pass x 2 paired passes (qt, 15-qt) -> every block
//    does exactly 34 KV-iters (fixes R6's 56% load-balance stall) while
//    keeping R6's low K/V traffic and chunked-XCD L2 residency.
//  - everything else identical to R6.
//
// Frag layouts (verified, mfma_f32_16x16x32_bf16):
//   C/D: row = (lane>>4)*4 + j, col = lane&15
//   A:   row = lane&15,        k = (lane>>4)*8 + j
//   B:   col = lane&15,        k = (lane>>4)*8 + j

typedef __attribute__((ext_vector_type(8))) short bf16x8;
typedef __attribute__((ext_vector_type(4))) float f32x4;

#define LOG2E 1.4426950408889634f

__device__ __forceinline__ unsigned short f2bf(float f) {
  unsigned int u = __builtin_bit_cast(unsigned int, f);
  unsigned int r = (u + 0x7FFFu + ((u >> 16) & 1u)) >> 16;  // RNE
  return (unsigned short)r;
}
__device__ __forceinline__ float bf2f(unsigned short h) {
  return __builtin_bit_cast(float, (unsigned int)h << 16);
}
__device__ __forceinline__ unsigned int packbf2(float a, float b) {
  return (unsigned int)f2bf(a) | ((unsigned int)f2bf(b) << 16);
}
// XOR swizzle for [R][64]-ushort row-major LDS tiles: byte ^= ((row&7)<<4).
__device__ __forceinline__ int swz(int idx) {
  return idx ^ (((idx >> 6) & 7) << 3);
}

// ---------------- fp32 -> bf16 bulk converts ----------------
__global__ __launch_bounds__(256) void cvt_kernel(const float* __restrict__ in,
                                                  unsigned short* __restrict__ out,
                                                  int n8) {
  int i = blockIdx.x * 256 + threadIdx.x;
  if (i < n8) {
    float4 u0 = ((const float4*)in)[i * 2];
    float4 u1 = ((const float4*)in)[i * 2 + 1];
    uint4 v = {packbf2(u0.x, u0.y), packbf2(u0.z, u0.w),
               packbf2(u1.x, u1.y), packbf2(u1.z, u1.w)};
    ((uint4*)out)[i] = v;
  }
}
// Convert Wq/Wk/Wv (1M fp32 each) -> bf16, dst selected by blockIdx.y.
__global__ __launch_bounds__(256) void cvt_w3(const float* __restrict__ w0,
                                              const float* __restrict__ w1,
                                              const float* __restrict__ w2,
                                              unsigned short* __restrict__ dst) {
  const float* src = blockIdx.y == 0 ? w0 : (blockIdx.y == 1 ? w1 : w2);
  unsigned short* d = dst + (size_t)blockIdx.y * 1024 * 1024;
  int i = blockIdx.x * 256 + threadIdx.x;
  float4 u0 = ((const float4*)src)[i * 2];
  float4 u1 = ((const float4*)src)[i * 2 + 1];
  uint4 v = {packbf2(u0.x, u0.y), packbf2(u0.z, u0.w),
             packbf2(u1.x, u1.y), packbf2(u1.z, u1.w)};
  ((uint4*)d)[i] = v;
}

// ---------------- fused QKV GEMM ----------------
// C = Xb[8192,1024](bf16) * W[3072,1024]^T(bf16). 128x128 tile, BK=64, 4 waves.
__global__ __launch_bounds__(256) void gemm_qkv(const unsigned short* __restrict__ Xb,
                                                const unsigned short* __restrict__ Wb3,
                                                unsigned short* __restrict__ Qb,
                                                unsigned short* __restrict__ Kb,
                                                unsigned short* __restrict__ Vtb) {
  __shared__ alignas(16) unsigned short As[128 * 64];
  __shared__ alignas(16) unsigned short Bs[128 * 64];
  const int t = threadIdx.x;
  const int lane = t & 63;
  const int w = t >> 6;
  const int wr = w >> 1, wc = w & 1;
  const int fr = lane & 15, fq = lane >> 4;
  const int m0 = blockIdx.x * 128;
  const int sel = blockIdx.y >> 3;
  const int n0 = (blockIdx.y & 7) * 128;
  const unsigned short* Wp = Wb3 + (size_t)sel * 1024 * 1024;
  const int K = 1024;

  const f32x4 zero = {0.f, 0.f, 0.f, 0.f};
  f32x4 acc[4][4];
#pragma unroll
  for (int m = 0; m < 4; ++m)
#pragma unroll
    for (int n = 0; n < 4; ++n) acc[m][n] = zero;

  for (int k0 = 0; k0 < K; k0 += 64) {
#pragma unroll
    for (int cc = 0; cc < 4; ++cc) {
      int c = w * 4 + cc;
      int flat = c * 512 + lane * 8;
      int row = flat >> 6, col = flat & 63;
      __builtin_amdgcn_global_load_lds(
          (const __attribute__((address_space(1))) void*)(Xb + (size_t)(m0 + row) * K + (k0 + col)),
          (__attribute__((address_space(3))) void*)&As[c * 512], 16, 0, 0);
      __builtin_amdgcn_global_load_lds(
          (const __attribute__((address_space(1))) void*)(Wp + (size_t)(n0 + row) * K + (k0 + col)),
          (__attribute__((address_space(3))) void*)&Bs[c * 512], 16, 0, 0);
    }
    __syncthreads();
#pragma unroll
    for (int kk = 0; kk < 2; ++kk) {
      bf16x8 a[4], b[4];
#pragma unroll
      for (int m = 0; m < 4; ++m)
        a[m] = *(const bf16x8*)&As[(wr * 64 + m * 16 + fr) * 64 + kk * 32 + fq * 8];
#pragma unroll
      for (int n = 0; n < 4; ++n)
        b[n] = *(const bf16x8*)&Bs[(wc * 64 + n * 16 + fr) * 64 + kk * 32 + fq * 8];
#pragma unroll
      for (int m = 0; m < 4; ++m)
#pragma unroll
        for (int n = 0; n < 4; ++n)
          acc[m][n] = __builtin_amdgcn_mfma_f32_16x16x32_bf16(a[m], b[n], acc[m][n], 0, 0, 0);
    }
    __syncthreads();
  }

#pragma unroll
  for (int m = 0; m < 4; ++m)
#pragma unroll
    for (int n = 0; n < 4; ++n) {
      int row = m0 + wr * 64 + m * 16 + fq * 4;
      int col = n0 + wc * 64 + n * 16 + fr;
      if (sel < 2) {
        unsigned short* Cp = sel ? Kb : Qb;
#pragma unroll
        for (int j = 0; j < 4; ++j)
          Cp[(size_t)(row + j) * 1024 + col] = f2bf(acc[m][n][j]);
      } else {
        int b = row >> 11, s = row & 2047;
        int h = col >> 6, d = col & 63;
        ushort4 v4 = {f2bf(acc[m][n][0]), f2bf(acc[m][n][1]),
                      f2bf(acc[m][n][2]), f2bf(acc[m][n][3])};
        *(ushort4*)&Vtb[(((size_t)b * 16 + h) * 64 + d) * 2048 + s] = v4;
      }
    }
}

// ---------------- RoPE (in-place, 4 pairs/thread) ----------------
// Q additionally scaled by (1/sqrt(d_k))*log2(e) so attn can use exp2 directly.
__global__ __launch_bounds__(256) void rope_kernel(unsigned short* __restrict__ Q,
                                                   unsigned short* __restrict__ Kb,
                                                   const int* __restrict__ tp) {
  int idx = blockIdx.x * 256 + threadIdx.x;
  unsigned short* ptr = blockIdx.y ? Kb : Q;
  const float scale = blockIdx.y ? 1.0f : 0.125f * LOG2E;
  int flat8 = idx * 8;
  int r = flat8 >> 10;
  int colbase = flat8 & 1023;
  int ibase = (colbase & 63) >> 1;
  int s = r & 2047;
  float pos = (float)tp[s];
  const float cexp = -13.287712379549449f / 32.0f;  // -log2(theta)/32

  uint4 v = *(const uint4*)&ptr[flat8];
  unsigned int* vp = (unsigned int*)&v;
  uint4 o;
  unsigned int* op = (unsigned int*)&o;
#pragma unroll
  for (int p = 0; p < 4; ++p) {
    float inv = exp2f((float)(ibase + p) * cexp);
    float ang = pos * inv;
    float sn, cs;
    sincosf(ang, &sn, &cs);
    float x1 = bf2f((unsigned short)(vp[p] & 0xFFFFu));
    float x2 = bf2f((unsigned short)(vp[p] >> 16));
    op[p] = packbf2((x1 * cs - x2 * sn) * scale, (x1 * sn + x2 * cs) * scale);
  }
  *(uint4*)&ptr[flat8] = o;
}

// ---------------- Flash attention, causal, paired 128-row q-tiles ----------------
// 256 threads = 4 waves; wave w owns rows q0+w*32..+31 (2 groups of 16).
// Two passes: qt and 15-qt -> exactly 34 KV-iters per block (balanced).
// Swapped QK^T: lane's q = fr; kv = n*16+fq*4+j. Chunked XCD block mapping.
__global__ __launch_bounds__(256) void attn_kernel(const unsigned short* __restrict__ Q,
                                                   const unsigned short* __restrict__ K,
                                                   const unsigned short* __restrict__ Vt_g,
                                                   unsigned short* __restrict__ O) {
  __shared__ alignas(16) unsigned short Ks[64 * 64];
  __shared__ alignas(16) unsigned short Vt[64 * 64];   // [d][kv]
  const int t = threadIdx.x;
  const int lane = t & 63, w = t >> 6;
  const int fr = lane & 15, fq = lane >> 4;
  // chunked XCD mapping: 512 blocks; XCD k gets gblk in [64k,64k+64) =
  // 8 whole (b,h) groups (8 pair-blocks each) -> KV L2-resident per XCD.
  const int gblk = (blockIdx.x & 7) * 64 + (blockIdx.x >> 3);
  const int pairidx = gblk & 7;
  const int hb = gblk >> 3;
  const int h = hb & 15, b = hb >> 4;
  const size_t base = ((size_t)b * 2048) * 1024 + (size_t)h * 64;
  const size_t vbase = ((size_t)b * 16 + h) * 64 * 2048;
  const f32x4 zero = {0.f, 0.f, 0.f, 0.f};

  const int sflat = t * 8;               // staging: 2 chunks of 2048 elems
  const int srow0 = sflat >> 6, scol = sflat & 63;

  for (int pass = 0; pass < 2; ++pass) {
    const int qt = pass ? (15 - pairidx) : pairidx;
    const int q0 = qt * 128;
    const int wq = q0 + w * 32;
    const int kvend = q0 + 128;

    // Q frags straight from global (16B contiguous per lane).
    bf16x8 qf[2][2];
#pragma unroll
    for (int g = 0; g < 2; ++g)
#pragma unroll
      for (int kk = 0; kk < 2; ++kk)
        qf[g][kk] = *(const bf16x8*)&Q[base + (size_t)(q0 + w * 32 + g * 16 + fr) * 1024 + kk * 32 + fq * 8];

    float m_[2] = {-INFINITY, -INFINITY};
    float l_[2] = {0.f, 0.f};
    f32x4 oaccT[2][4];
#pragma unroll
    for (int g = 0; g < 2; ++g)
#pragma unroll
      for (int n = 0; n < 4; ++n) oaccT[g][n] = zero;

    // prefetch tile 0 of this pass
    uint4 kr[2], vr[2];
#pragma unroll
    for (int it = 0; it < 2; ++it) {
      int row = srow0 + it * 32;
      kr[it] = *(const uint4*)&K[base + (size_t)row * 1024 + scol];
      vr[it] = *(const uint4*)&Vt_g[vbase + (size_t)row * 2048 + scol];
    }

    for (int kv0 = 0; kv0 < kvend; kv0 += 64) {
      __syncthreads();
#pragma unroll
      for (int it = 0; it < 2; ++it) {
        int flat = sflat + it * 2048;
        *(uint4*)&Ks[swz(flat)] = kr[it];
        *(uint4*)&Vt[swz(flat)] = vr[it];
      }
      __syncthreads();
      if (kv0 + 64 < kvend) {
#pragma unroll
        for (int it = 0; it < 2; ++it) {
          int row = srow0 + it * 32;
          kr[it] = *(const uint4*)&K[base + (size_t)(kv0 + 64 + row) * 1024 + scol];
          vr[it] = *(const uint4*)&Vt_g[vbase + (size_t)row * 2048 + kv0 + 64 + scol];
        }
      }

      if (kv0 <= wq + 31) {  // some group in this wave still unmasked
        // shared K frags for both groups
        bf16x8 kf[2][4];
#pragma unroll
        for (int kk = 0; kk < 2; ++kk)
#pragma unroll
          for (int n = 0; n < 4; ++n)
            kf[kk][n] = *(const bf16x8*)&Ks[swz((n * 16 + fr) * 64 + kk * 32 + fq * 8)];

#pragma unroll
        for (int g = 0; g < 2; ++g) {
          if (kv0 > wq + g * 16 + 15) continue;  // fully masked for this group
          // ---- S^T = K Q^T ----
          f32x4 sa[4];
#pragma unroll
          for (int n = 0; n < 4; ++n) sa[n] = zero;
#pragma unroll
          for (int kk = 0; kk < 2; ++kk)
#pragma unroll
            for (int n = 0; n < 4; ++n)
              sa[n] = __builtin_amdgcn_mfma_f32_16x16x32_bf16(kf[kk][n], qf[g][kk], sa[n], 0, 0, 0);

          // ---- causal mask + online softmax (exp2 domain; row local to lane) ----
          const int dd = kv0 - wq - g * 16;    // kv_global - q_base of group
          const bool diag = (dd > -63);
          float pmax = -3.0e38f;
#pragma unroll
          for (int n = 0; n < 4; ++n)
#pragma unroll
            for (int j = 0; j < 4; ++j) {
              float s = sa[n][j];
              if (diag && (n * 16 + fq * 4 + j + dd > fr)) s = -3.0e38f;
              sa[n][j] = s;
              pmax = fmaxf(pmax, s);
            }
          pmax = fmaxf(pmax, __shfl_xor(pmax, 16));
          pmax = fmaxf(pmax, __shfl_xor(pmax, 32));
          float mn = fmaxf(m_[g], pmax);
          float alpha = exp2f(m_[g] - mn);
          m_[g] = mn;
          float ps = 0.f;
#pragma unroll
          for (int n = 0; n < 4; ++n)
#pragma unroll
            for (int j = 0; j < 4; ++j) {
              float e = exp2f(sa[n][j] - mn);
              sa[n][j] = e;
              ps += e;
            }
          ps += __shfl_xor(ps, 16);
          ps += __shfl_xor(ps, 32);
          l_[g] = l_[g] * alpha + ps;
#pragma unroll
          for (int n = 0; n < 4; ++n)
#pragma unroll
            for (int j = 0; j < 4; ++j) oaccT[g][n][j] *= alpha;

          // ---- P^T -> PV B-frag: in-register butterfly (verified R4/R5) ----
          unsigned R[4][2], F[4][2];
#pragma unroll
          for (int n = 0; n < 4; ++n)
#pragma unroll
            for (int pp = 0; pp < 2; ++pp)
              R[n][pp] = packbf2(sa[n][2 * pp], sa[n][2 * pp + 1]);
#pragma unroll
          for (int pp = 0; pp < 2; ++pp) {
            unsigned t0 = (fq < 2) ? R[1][pp] : R[0][pp];
            unsigned t1 = (fq < 2) ? R[3][pp] : R[2][pp];
            t0 = (unsigned)__shfl_xor((int)t0, 32);
            t1 = (unsigned)__shfl_xor((int)t1, 32);
            unsigned G0 = (fq < 2) ? R[0][pp] : t0;
            unsigned G1 = (fq < 2) ? t0 : R[1][pp];
            unsigned G2 = (fq < 2) ? R[2][pp] : t1;
            unsigned G3 = (fq < 2) ? t1 : R[3][pp];
            unsigned u0 = ((fq & 1) == 0) ? G1 : G0;
            unsigned u1 = ((fq & 1) == 0) ? G3 : G2;
            u0 = (unsigned)__shfl_xor((int)u0, 16);
            u1 = (unsigned)__shfl_xor((int)u1, 16);
            F[0][pp] = ((fq & 1) == 0) ? G0 : u0;
            F[1][pp] = ((fq & 1) == 0) ? u0 : G1;
            F[2][pp] = ((fq & 1) == 0) ? G2 : u1;
            F[3][pp] = ((fq & 1) == 0) ? u1 : G3;
          }
          union U8 { unsigned u[4]; bf16x8 v; };
          U8 pb0, pb1;
          pb0.u[0] = F[0][0]; pb0.u[1] = F[0][1]; pb0.u[2] = F[1][0]; pb0.u[3] = F[1][1];
          pb1.u[0] = F[2][0]; pb1.u[1] = F[2][1]; pb1.u[2] = F[3][0]; pb1.u[3] = F[3][1];

          // ---- O^T += V^T P^T ----
#pragma unroll
          for (int n = 0; n < 4; ++n) {
            bf16x8 vf0 = *(const bf16x8*)&Vt[swz((n * 16 + fr) * 64 + 0 * 32 + fq * 8)];
            oaccT[g][n] = __builtin_amdgcn_mfma_f32_16x16x32_bf16(vf0, pb0.v, oaccT[g][n], 0, 0, 0);
            bf16x8 vf1 = *(const bf16x8*)&Vt[swz((n * 16 + fr) * 64 + 1 * 32 + fq * 8)];
            oaccT[g][n] = __builtin_amdgcn_mfma_f32_16x16x32_bf16(vf1, pb1.v, oaccT[g][n], 0, 0, 0);
          }
        }
      }
    }

    // ---- epilogue ----
#pragma unroll
    for (int g = 0; g < 2; ++g) {
      float rl = 1.0f / l_[g];
#pragma unroll
      for (int n = 0; n < 4; ++n) {
        ushort4 v4 = {f2bf(oaccT[g][n][0] * rl), f2bf(oaccT[g][n][1] * rl),
                      f2bf(oaccT[g][n][2] * rl), f2bf(oaccT[g][n][3] * rl)};
        *(ushort4*)&O[base + (size_t)(q0 + w * 32 + g * 16 + fr) * 1024 + n * 16 + fq * 4] = v4;
      }
    }
  }
}

// ---------------- out GEMM: C fp32 = A(bf16) * W(bf16)^T ----------------
__global__ __launch_bounds__(256) void gemm_out_bf(const unsigned short* __restrict__ Ap,
                                                   const unsigned short* __restrict__ Wp,
                                                   float* __restrict__ Cp) {
  __shared__ alignas(16) unsigned short As[128 * 64];
  __shared__ alignas(16) unsigned short Bs[128 * 64];
  const int t = threadIdx.x;
  const int lane = t & 63;
  const int w = t >> 6;
  const int wr = w >> 1, wc = w & 1;
  const int fr = lane & 15, fq = lane >> 4;
  const int m0 = blockIdx.x * 128, n0 = blockIdx.y * 128;
  const int K = 1024, N = 1024;

  const f32x4 zero = {0.f, 0.f, 0.f, 0.f};
  f32x4 acc[4][4];
#pragma unroll
  for (int m = 0; m < 4; ++m)
#pragma unroll
    for (int n = 0; n < 4; ++n) acc[m][n] = zero;

  for (int k0 = 0; k0 < K; k0 += 64) {
#pragma unroll
    for (int cc = 0; cc < 4; ++cc) {
      int c = w * 4 + cc;
      int flat = c * 512 + lane * 8;
      int row = flat >> 6, col = flat & 63;
      __builtin_amdgcn_global_load_lds(
          (const __attribute__((address_space(1))) void*)(Ap + (size_t)(m0 + row) * K + (k0 + col)),
          (__attribute__((address_space(3))) void*)&As[c * 512], 16, 0, 0);
      __builtin_amdgcn_global_load_lds(
          (const __attribute__((address_space(1))) void*)(Wp + (size_t)(n0 + row) * K + (k0 + col)),
          (__attribute__((address_space(3))) void*)&Bs[c * 512], 16, 0, 0);
    }
    __syncthreads();
#pragma unroll
    for (int kk = 0; kk < 2; ++kk) {
      bf16x8 a[4], b[4];
#pragma unroll
      for (int m = 0; m < 4; ++m)
        a[m] = *(const bf16x8*)&As[(wr * 64 + m * 16 + fr) * 64 + kk * 32 + fq * 8];
#pragma unroll
      for (int n = 0; n < 4; ++n)
        b[n] = *(const bf16x8*)&Bs[(wc * 64 + n * 16 + fr) * 64 + kk * 32 + fq * 8];
#pragma unroll
      for (int m = 0; m < 4; ++m)
#pragma unroll
        for (int n = 0; n < 4; ++n)
          acc[m][n] = __builtin_amdgcn_mfma_f32_16x16x32_bf16(a[m], b[n], acc[m][n], 0, 0, 0);
    }
    __syncthreads();
  }

#pragma unroll
  for (int m = 0; m < 4; ++m)
#pragma unroll
    for (int n = 0; n < 4; ++n) {
      int row = m0 + wr * 64 + m * 16 + fq * 4;
      int col = n0 + wc * 64 + n * 16 + fr;
#pragma unroll
      for (int j = 0; j < 4; ++j)
        Cp[(size_t)(row + j) * N + col] = acc[m][n][j];
    }
}

extern "C" void kernel_launch(void* const* d_in, const int* in_sizes, int n_in,
                              void* d_out, int out_size, void* d_ws, size_t ws_size,
                              hipStream_t stream) {
  const float* x  = (const float*)d_in[0];
  const int* tp   = (const int*)d_in[1];
  const float* Wq = (const float*)d_in[2];
  const float* Wk = (const float*)d_in[3];
  const float* Wv = (const float*)d_in[4];
  const float* Wo = (const float*)d_in[5];
  float* out = (float*)d_out;

  const size_t MAT = (size_t)8192 * 1024;
  unsigned short* Qb  = (unsigned short*)d_ws;
  unsigned short* Kb  = Qb + MAT;
  unsigned short* Vtb = Kb + MAT;          // V^T (B,H,64,2048)
  unsigned short* Xb  = Vtb + MAT;         // x bf16; reused as Ob after gemm_qkv
  unsigned short* Ob  = Xb;
  unsigned short* Wb3 = (unsigned short*)d_out;  // Wq/Wk/Wv bf16 (6 MB of 32 MB, dead before gemm_out)
  unsigned short* WoB = Qb;                // Wo bf16 after attn (Qb dead)

  cvt_kernel<<<4096, 256, 0, stream>>>(x, Xb, 8192 * 1024 / 8);
  cvt_w3<<<dim3(512, 3), 256, 0, stream>>>(Wq, Wk, Wv, Wb3);
  gemm_qkv<<<dim3(64, 24), 256, 0, stream>>>(Xb, Wb3, Qb, Kb, Vtb);
  rope_kernel<<<dim3(4096, 2), 256, 0, stream>>>(Qb, Kb, tp);
  attn_kernel<<<512, 256, 0, stream>>>(Qb, Kb, Vtb, Ob);
  cvt_kernel<<<512, 256, 0, stream>>>(Wo, WoB, 1024 * 1024 / 8);
  gemm_out_bf<<<dim3(64, 8), 256, 0, stream>>>(Ob, WoB, out);
}

// Round 10
// 344.806 us; speedup vs baseline: 1.1990x; 1.0562x over previous
//
#include <hip/hip_runtime.h>
#include <cstdint>
#include <cstddef>

// MultiHeadSelfAttention forward, MI355X/gfx950.  Round 10.
//  - attn VALU cuts (was VALUBusy 53% vs MfmaUtil 9%): v_cvt_pk_bf16_f32 for
//    P->bf16 (80->8 ops), wave-uniform causal-mask guard (skips 32 ops in >90%
//    of tiles), T13 defer-rescale (skips alpha path ~80% of tiles).
//  - everything else identical to R9 (paired 128-row q-tiles, chunked XCD).
//
// Frag layouts (verified, mfma_f32_16x16x32_bf16):
//   C/D: row = (lane>>4)*4 + j, col = lane&15
//   A:   row = lane&15,        k = (lane>>4)*8 + j
//   B:   col = lane&15,        k = (lane>>4)*8 + j

typedef __attribute__((ext_vector_type(8))) short bf16x8;
typedef __attribute__((ext_vector_type(4))) float f32x4;

#define LOG2E 1.4426950408889634f

__device__ __forceinline__ unsigned short f2bf(float f) {
  unsigned int u = __builtin_bit_cast(unsigned int, f);
  unsigned int r = (u + 0x7FFFu + ((u >> 16) & 1u)) >> 16;  // RNE
  return (unsigned short)r;
}
__device__ __forceinline__ float bf2f(unsigned short h) {
  return __builtin_bit_cast(float, (unsigned int)h << 16);
}
__device__ __forceinline__ unsigned int packbf2(float a, float b) {
  return (unsigned int)f2bf(a) | ((unsigned int)f2bf(b) << 16);
}
// HW packed f32->bf16 (RNE), 1 instr for 2 values (T12 recipe; no builtin).
__device__ __forceinline__ unsigned int cvtpk(float lo, float hi) {
  unsigned int r;
  asm("v_cvt_pk_bf16_f32 %0, %1, %2" : "=v"(r) : "v"(lo), "v"(hi));
  return r;
}
// XOR swizzle for [R][64]-ushort row-major LDS tiles: byte ^= ((row&7)<<4).
__device__ __forceinline__ int swz(int idx) {
  return idx ^ (((idx >> 6) & 7) << 3);
}

// ---------------- fp32 -> bf16 bulk converts ----------------
__global__ __launch_bounds__(256) void cvt_kernel(const float* __restrict__ in,
                                                  unsigned short* __restrict__ out,
                                                  int n8) {
  int i = blockIdx.x * 256 + threadIdx.x;
  if (i < n8) {
    float4 u0 = ((const float4*)in)[i * 2];
    float4 u1 = ((const float4*)in)[i * 2 + 1];
    uint4 v = {packbf2(u0.x, u0.y), packbf2(u0.z, u0.w),
               packbf2(u1.x, u1.y), packbf2(u1.z, u1.w)};
    ((uint4*)out)[i] = v;
  }
}
// Convert Wq/Wk/Wv (1M fp32 each) -> bf16, dst selected by blockIdx.y.
__global__ __launch_bounds__(256) void cvt_w3(const float* __restrict__ w0,
                                              const float* __restrict__ w1,
                                              const float* __restrict__ w2,
                                              unsigned short* __restrict__ dst) {
  const float* src = blockIdx.y == 0 ? w0 : (blockIdx.y == 1 ? w1 : w2);
  unsigned short* d = dst + (size_t)blockIdx.y * 1024 * 1024;
  int i = blockIdx.x * 256 + threadIdx.x;
  float4 u0 = ((const float4*)src)[i * 2];
  float4 u1 = ((const float4*)src)[i * 2 + 1];
  uint4 v = {packbf2(u0.x, u0.y), packbf2(u0.z, u0.w),
             packbf2(u1.x, u1.y), packbf2(u1.z, u1.w)};
  ((uint4*)d)[i] = v;
}

// ---------------- fused QKV GEMM ----------------
// C = Xb[8192,1024](bf16) * W[3072,1024]^T(bf16). 128x128 tile, BK=64, 4 waves.
__global__ __launch_bounds__(256) void gemm_qkv(const unsigned short* __restrict__ Xb,
                                                const unsigned short* __restrict__ Wb3,
                                                unsigned short* __restrict__ Qb,
                                                unsigned short* __restrict__ Kb,
                                                unsigned short* __restrict__ Vtb) {
  __shared__ alignas(16) unsigned short As[128 * 64];
  __shared__ alignas(16) unsigned short Bs[128 * 64];
  const int t = threadIdx.x;
  const int lane = t & 63;
  const int w = t >> 6;
  const int wr = w >> 1, wc = w & 1;
  const int fr = lane & 15, fq = lane >> 4;
  const int m0 = blockIdx.x * 128;
  const int sel = blockIdx.y >> 3;
  const int n0 = (blockIdx.y & 7) * 128;
  const unsigned short* Wp = Wb3 + (size_t)sel * 1024 * 1024;
  const int K = 1024;

  const f32x4 zero = {0.f, 0.f, 0.f, 0.f};
  f32x4 acc[4][4];
#pragma unroll
  for (int m = 0; m < 4; ++m)
#pragma unroll
    for (int n = 0; n < 4; ++n) acc[m][n] = zero;

  for (int k0 = 0; k0 < K; k0 += 64) {
#pragma unroll
    for (int cc = 0; cc < 4; ++cc) {
      int c = w * 4 + cc;
      int flat = c * 512 + lane * 8;
      int row = flat >> 6, col = flat & 63;
      __builtin_amdgcn_global_load_lds(
          (const __attribute__((address_space(1))) void*)(Xb + (size_t)(m0 + row) * K + (k0 + col)),
          (__attribute__((address_space(3))) void*)&As[c * 512], 16, 0, 0);
      __builtin_amdgcn_global_load_lds(
          (const __attribute__((address_space(1))) void*)(Wp + (size_t)(n0 + row) * K + (k0 + col)),
          (__attribute__((address_space(3))) void*)&Bs[c * 512], 16, 0, 0);
    }
    __syncthreads();
#pragma unroll
    for (int kk = 0; kk < 2; ++kk) {
      bf16x8 a[4], b[4];
#pragma unroll
      for (int m = 0; m < 4; ++m)
        a[m] = *(const bf16x8*)&As[(wr * 64 + m * 16 + fr) * 64 + kk * 32 + fq * 8];
#pragma unroll
      for (int n = 0; n < 4; ++n)
        b[n] = *(const bf16x8*)&Bs[(wc * 64 + n * 16 + fr) * 64 + kk * 32 + fq * 8];
#pragma unroll
      for (int m = 0; m < 4; ++m)
#pragma unroll
        for (int n = 0; n < 4; ++n)
          acc[m][n] = __builtin_amdgcn_mfma_f32_16x16x32_bf16(a[m], b[n], acc[m][n], 0, 0, 0);
    }
    __syncthreads();
  }

#pragma unroll
  for (int m = 0; m < 4; ++m)
#pragma unroll
    for (int n = 0; n < 4; ++n) {
      int row = m0 + wr * 64 + m * 16 + fq * 4;
      int col = n0 + wc * 64 + n * 16 + fr;
      if (sel < 2) {
        unsigned short* Cp = sel ? Kb : Qb;
#pragma unroll
        for (int j = 0; j < 4; ++j)
          Cp[(size_t)(row + j) * 1024 + col] = f2bf(acc[m][n][j]);
      } else {
        int b = row >> 11, s = row & 2047;
        int h = col >> 6, d = col & 63;
        ushort4 v4 = {f2bf(acc[m][n][0]), f2bf(acc[m][n][1]),
                      f2bf(acc[m][n][2]), f2bf(acc[m][n][3])};
        *(ushort4*)&Vtb[(((size_t)b * 16 + h) * 64 + d) * 2048 + s] = v4;
      }
    }
}

// ---------------- RoPE (in-place, 4 pairs/thread) ----------------
// Q additionally scaled by (1/sqrt(d_k))*log2(e) so attn can use exp2 directly.
__global__ __launch_bounds__(256) void rope_kernel(unsigned short* __restrict__ Q,
                                                   unsigned short* __restrict__ Kb,
                                                   const int* __restrict__ tp) {
  int idx = blockIdx.x * 256 + threadIdx.x;
  unsigned short* ptr = blockIdx.y ? Kb : Q;
  const float scale = blockIdx.y ? 1.0f : 0.125f * LOG2E;
  int flat8 = idx * 8;
  int r = flat8 >> 10;
  int colbase = flat8 & 1023;
  int ibase = (colbase & 63) >> 1;
  int s = r & 2047;
  float pos = (float)tp[s];
  const float cexp = -13.287712379549449f / 32.0f;  // -log2(theta)/32

  uint4 v = *(const uint4*)&ptr[flat8];
  unsigned int* vp = (unsigned int*)&v;
  uint4 o;
  unsigned int* op = (unsigned int*)&o;
#pragma unroll
  for (int p = 0; p < 4; ++p) {
    float inv = exp2f((float)(ibase + p) * cexp);
    float ang = pos * inv;
    float sn, cs;
    sincosf(ang, &sn, &cs);
    float x1 = bf2f((unsigned short)(vp[p] & 0xFFFFu));
    float x2 = bf2f((unsigned short)(vp[p] >> 16));
    op[p] = packbf2((x1 * cs - x2 * sn) * scale, (x1 * sn + x2 * cs) * scale);
  }
  *(uint4*)&ptr[flat8] = o;
}

// ---------------- Flash attention, causal, paired 128-row q-tiles ----------------
// 256 threads = 4 waves; wave w owns rows q0+w*32..+31 (2 groups of 16).
// Two passes: qt and 15-qt -> exactly 34 KV-iters per block (balanced).
// Swapped QK^T: lane's q = fr; kv = n*16+fq*4+j. Chunked XCD block mapping.
__global__ __launch_bounds__(256) void attn_kernel(const unsigned short* __restrict__ Q,
                                                   const unsigned short* __restrict__ K,
                                                   const unsigned short* __restrict__ Vt_g,
                                                   unsigned short* __restrict__ O) {
  __shared__ alignas(16) unsigned short Ks[64 * 64];
  __shared__ alignas(16) unsigned short Vt[64 * 64];   // [d][kv]
  const int t = threadIdx.x;
  const int lane = t & 63, w = t >> 6;
  const int fr = lane & 15, fq = lane >> 4;
  // chunked XCD mapping: 512 blocks; XCD k gets gblk in [64k,64k+64) =
  // 8 whole (b,h) groups (8 pair-blocks each) -> KV L2-resident per XCD.
  const int gblk = (blockIdx.x & 7) * 64 + (blockIdx.x >> 3);
  const int pairidx = gblk & 7;
  const int hb = gblk >> 3;
  const int h = hb & 15, b = hb >> 4;
  const size_t base = ((size_t)b * 2048) * 1024 + (size_t)h * 64;
  const size_t vbase = ((size_t)b * 16 + h) * 64 * 2048;
  const f32x4 zero = {0.f, 0.f, 0.f, 0.f};

  const int sflat = t * 8;               // staging: 2 chunks of 2048 elems
  const int srow0 = sflat >> 6, scol = sflat & 63;

  for (int pass = 0; pass < 2; ++pass) {
    const int qt = pass ? (15 - pairidx) : pairidx;
    const int q0 = qt * 128;
    const int wq = q0 + w * 32;
    const int kvend = q0 + 128;

    // Q frags straight from global (16B contiguous per lane).
    bf16x8 qf[2][2];
#pragma unroll
    for (int g = 0; g < 2; ++g)
#pragma unroll
      for (int kk = 0; kk < 2; ++kk)
        qf[g][kk] = *(const bf16x8*)&Q[base + (size_t)(q0 + w * 32 + g * 16 + fr) * 1024 + kk * 32 + fq * 8];

    float m_[2] = {-INFINITY, -INFINITY};
    float l_[2] = {0.f, 0.f};
    f32x4 oaccT[2][4];
#pragma unroll
    for (int g = 0; g < 2; ++g)
#pragma unroll
      for (int n = 0; n < 4; ++n) oaccT[g][n] = zero;

    // prefetch tile 0 of this pass
    uint4 kr[2], vr[2];
#pragma unroll
    for (int it = 0; it < 2; ++it) {
      int row = srow0 + it * 32;
      kr[it] = *(const uint4*)&K[base + (size_t)row * 1024 + scol];
      vr[it] = *(const uint4*)&Vt_g[vbase + (size_t)row * 2048 + scol];
    }

    for (int kv0 = 0; kv0 < kvend; kv0 += 64) {
      __syncthreads();
#pragma unroll
      for (int it = 0; it < 2; ++it) {
        int flat = sflat + it * 2048;
        *(uint4*)&Ks[swz(flat)] = kr[it];
        *(uint4*)&Vt[swz(flat)] = vr[it];
      }
      __syncthreads();
      if (kv0 + 64 < kvend) {
#pragma unroll
        for (int it = 0; it < 2; ++it) {
          int row = srow0 + it * 32;
          kr[it] = *(const uint4*)&K[base + (size_t)(kv0 + 64 + row) * 1024 + scol];
          vr[it] = *(const uint4*)&Vt_g[vbase + (size_t)row * 2048 + kv0 + 64 + scol];
        }
      }

      if (kv0 <= wq + 31) {  // some group in this wave still unmasked
        // shared K frags for both groups
        bf16x8 kf[2][4];
#pragma unroll
        for (int kk = 0; kk < 2; ++kk)
#pragma unroll
          for (int n = 0; n < 4; ++n)
            kf[kk][n] = *(const bf16x8*)&Ks[swz((n * 16 + fr) * 64 + kk * 32 + fq * 8)];

#pragma unroll
        for (int g = 0; g < 2; ++g) {
          if (kv0 > wq + g * 16 + 15) continue;  // fully masked for this group
          // ---- S^T = K Q^T ----
          f32x4 sa[4];
#pragma unroll
          for (int n = 0; n < 4; ++n) sa[n] = zero;
#pragma unroll
          for (int kk = 0; kk < 2; ++kk)
#pragma unroll
            for (int n = 0; n < 4; ++n)
              sa[n] = __builtin_amdgcn_mfma_f32_16x16x32_bf16(kf[kk][n], qf[g][kk], sa[n], 0, 0, 0);

          // ---- causal mask: wave-uniform guard (only ~1-2 of 34 tiles) ----
          const int dd = kv0 - wq - g * 16;    // kv_global - q_base of group
          if (dd > -63) {
#pragma unroll
            for (int n = 0; n < 4; ++n)
#pragma unroll
              for (int j = 0; j < 4; ++j)
                if (n * 16 + fq * 4 + j + dd > fr) sa[n][j] = -3.0e38f;
          }

          // ---- online softmax, T13 defer-rescale ----
          float pmax = -3.0e38f;
#pragma unroll
          for (int n = 0; n < 4; ++n)
#pragma unroll
            for (int j = 0; j < 4; ++j) pmax = fmaxf(pmax, sa[n][j]);
          pmax = fmaxf(pmax, __shfl_xor(pmax, 16));
          pmax = fmaxf(pmax, __shfl_xor(pmax, 32));
          if (!__all(pmax <= m_[g])) {   // max grew for some row: rescale
            float mn = fmaxf(m_[g], pmax);
            float alpha = exp2f(m_[g] - mn);
            m_[g] = mn;
            l_[g] *= alpha;
#pragma unroll
            for (int n = 0; n < 4; ++n)
#pragma unroll
              for (int j = 0; j < 4; ++j) oaccT[g][n][j] *= alpha;
          }
          float ps = 0.f;
#pragma unroll
          for (int n = 0; n < 4; ++n)
#pragma unroll
            for (int j = 0; j < 4; ++j) {
              float e = exp2f(sa[n][j] - m_[g]);
              sa[n][j] = e;
              ps += e;
            }
          ps += __shfl_xor(ps, 16);
          ps += __shfl_xor(ps, 32);
          l_[g] += ps;

          // ---- P^T -> PV B-frag: HW cvt_pk + butterfly (verified R4/R5) ----
          unsigned R[4][2], F[4][2];
#pragma unroll
          for (int n = 0; n < 4; ++n)
#pragma unroll
            for (int pp = 0; pp < 2; ++pp)
              R[n][pp] = cvtpk(sa[n][2 * pp], sa[n][2 * pp + 1]);
#pragma unroll
          for (int pp = 0; pp < 2; ++pp) {
            unsigned t0 = (fq < 2) ? R[1][pp] : R[0][pp];
            unsigned t1 = (fq < 2) ? R[3][pp] : R[2][pp];
            t0 = (unsigned)__shfl_xor((int)t0, 32);
            t1 = (unsigned)__shfl_xor((int)t1, 32);
            unsigned G0 = (fq < 2) ? R[0][pp] : t0;
            unsigned G1 = (fq < 2) ? t0 : R[1][pp];
            unsigned G2 = (fq < 2) ? R[2][pp] : t1;
            unsigned G3 = (fq < 2) ? t1 : R[3][pp];
            unsigned u0 = ((fq & 1) == 0) ? G1 : G0;
            unsigned u1 = ((fq & 1) == 0) ? G3 : G2;
            u0 = (unsigned)__shfl_xor((int)u0, 16);
            u1 = (unsigned)__shfl_xor((int)u1, 16);
            F[0][pp] = ((fq & 1) == 0) ? G0 : u0;
            F[1][pp] = ((fq & 1) == 0) ? u0 : G1;
            F[2][pp] = ((fq & 1) == 0) ? G2 : u1;
            F[3][pp] = ((fq & 1) == 0) ? u1 : G3;
          }
          union U8 { unsigned u[4]; bf16x8 v; };
          U8 pb0, pb1;
          pb0.u[0] = F[0][0]; pb0.u[1] = F[0][1]; pb0.u[2] = F[1][0]; pb0.u[3] = F[1][1];
          pb1.u[0] = F[2][0]; pb1.u[1] = F[2][1]; pb1.u[2] = F[3][0]; pb1.u[3] = F[3][1];

          // ---- O^T += V^T P^T ----
#pragma unroll
          for (int n = 0; n < 4; ++n) {
            bf16x8 vf0 = *(const bf16x8*)&Vt[swz((n * 16 + fr) * 64 + 0 * 32 + fq * 8)];
            oaccT[g][n] = __builtin_amdgcn_mfma_f32_16x16x32_bf16(vf0, pb0.v, oaccT[g][n], 0, 0, 0);
            bf16x8 vf1 = *(const bf16x8*)&Vt[swz((n * 16 + fr) * 64 + 1 * 32 + fq * 8)];
            oaccT[g][n] = __builtin_amdgcn_mfma_f32_16x16x32_bf16(vf1, pb1.v, oaccT[g][n], 0, 0, 0);
          }
        }
      }
    }

    // ---- epilogue ----
#pragma unroll
    for (int g = 0; g < 2; ++g) {
      float rl = 1.0f / l_[g];
#pragma unroll
      for (int n = 0; n < 4; ++n) {
        ushort4 v4 = {f2bf(oaccT[g][n][0] * rl), f2bf(oaccT[g][n][1] * rl),
                      f2bf(oaccT[g][n][2] * rl), f2bf(oaccT[g][n][3] * rl)};
        *(ushort4*)&O[base + (size_t)(q0 + w * 32 + g * 16 + fr) * 1024 + n * 16 + fq * 4] = v4;
      }
    }
  }
}

// ---------------- out GEMM: C fp32 = A(bf16) * W(bf16)^T ----------------
__global__ __launch_bounds__(256) void gemm_out_bf(const unsigned short* __restrict__ Ap,
                                                   const unsigned short* __restrict__ Wp,
                                                   float* __restrict__ Cp) {
  __shared__ alignas(16) unsigned short As[128 * 64];
  __shared__ alignas(16) unsigned short Bs[128 * 64];
  const int t = threadIdx.x;
  const int lane = t & 63;
  const int w = t >> 6;
  const int wr = w >> 1, wc = w & 1;
  const int fr = lane & 15, fq = lane >> 4;
  const int m0 = blockIdx.x * 128, n0 = blockIdx.y * 128;
  const int K = 1024, N = 1024;

  const f32x4 zero = {0.f, 0.f, 0.f, 0.f};
  f32x4 acc[4][4];
#pragma unroll
  for (int m = 0; m < 4; ++m)
#pragma unroll
    for (int n = 0; n < 4; ++n) acc[m][n] = zero;

  for (int k0 = 0; k0 < K; k0 += 64) {
#pragma unroll
    for (int cc = 0; cc < 4; ++cc) {
      int c = w * 4 + cc;
      int flat = c * 512 + lane * 8;
      int row = flat >> 6, col = flat & 63;
      __builtin_amdgcn_global_load_lds(
          (const __attribute__((address_space(1))) void*)(Ap + (size_t)(m0 + row) * K + (k0 + col)),
          (__attribute__((address_space(3))) void*)&As[c * 512], 16, 0, 0);
      __builtin_amdgcn_global_load_lds(
          (const __attribute__((address_space(1))) void*)(Wp + (size_t)(n0 + row) * K + (k0 + col)),
          (__attribute__((address_space(3))) void*)&Bs[c * 512], 16, 0, 0);
    }
    __syncthreads();
#pragma unroll
    for (int kk = 0; kk < 2; ++kk) {
      bf16x8 a[4], b[4];
#pragma unroll
      for (int m = 0; m < 4; ++m)
        a[m] = *(const bf16x8*)&As[(wr * 64 + m * 16 + fr) * 64 + kk * 32 + fq * 8];
#pragma unroll
      for (int n = 0; n < 4; ++n)
        b[n] = *(const bf16x8*)&Bs[(wc * 64 + n * 16 + fr) * 64 + kk * 32 + fq * 8];
#pragma unroll
      for (int m = 0; m < 4; ++m)
#pragma unroll
        for (int n = 0; n < 4; ++n)
          acc[m][n] = __builtin_amdgcn_mfma_f32_16x16x32_bf16(a[m], b[n], acc[m][n], 0, 0, 0);
    }
    __syncthreads();
  }

#pragma unroll
  for (int m = 0; m < 4; ++m)
#pragma unroll
    for (int n = 0; n < 4; ++n) {
      int row = m0 + wr * 64 + m * 16 + fq * 4;
      int col = n0 + wc * 64 + n * 16 + fr;
#pragma unroll
      for (int j = 0; j < 4; ++j)
        Cp[(size_t)(row + j) * N + col] = acc[m][n][j];
    }
}

extern "C" void kernel_launch(void* const* d_in, const int* in_sizes, int n_in,
                              void* d_out, int out_size, void* d_ws, size_t ws_size,
                              hipStream_t stream) {
  const float* x  = (const float*)d_in[0];
  const int* tp   = (const int*)d_in[1];
  const float* Wq = (const float*)d_in[2];
  const float* Wk = (const float*)d_in[3];
  const float* Wv = (const float*)d_in[4];
  const float* Wo = (const float*)d_in[5];
  float* out = (float*)d_out;

  const size_t MAT = (size_t)8192 * 1024;
  unsigned short* Qb  = (unsigned short*)d_ws;
  unsigned short* Kb  = Qb + MAT;
  unsigned short* Vtb = Kb + MAT;          // V^T (B,H,64,2048)
  unsigned short* Xb  = Vtb + MAT;         // x bf16; reused as Ob after gemm_qkv
  unsigned short* Ob  = Xb;
  unsigned short* Wb3 = (unsigned short*)d_out;  // Wq/Wk/Wv bf16 (6 MB of 32 MB, dead before gemm_out)
  unsigned short* WoB = Qb;                // Wo bf16 after attn (Qb dead)

  cvt_kernel<<<4096, 256, 0, stream>>>(x, Xb, 8192 * 1024 / 8);
  cvt_w3<<<dim3(512, 3), 256, 0, stream>>>(Wq, Wk, Wv, Wb3);
  gemm_qkv<<<dim3(64, 24), 256, 0, stream>>>(Xb, Wb3, Qb, Kb, Vtb);
  rope_kernel<<<dim3(4096, 2), 256, 0, stream>>>(Qb, Kb, tp);
  attn_kernel<<<512, 256, 0, stream>>>(Qb, Kb, Vtb, Ob);
  cvt_kernel<<<512, 256, 0, stream>>>(Wo, WoB, 1024 * 1024 / 8);
  gemm_out_bf<<<dim3(64, 8), 256, 0, stream>>>(Ob, WoB, out);
}